// Round 9
// baseline (143.182 us; speedup 1.0000x reference)
//
#include <hip/hip_runtime.h>
#include <hip/hip_bf16.h>

typedef __attribute__((ext_vector_type(8))) short bf16x8;
typedef __attribute__((ext_vector_type(4))) float f32x4;

// ---------------- ws layout ----------------
// F    : bf16 [32768][672]            @ 0          (44,040,192 B)
// W2   : bf16 [768][672]              @ 44,040,192 (1,032,192 B)
// biasT: f32  [768]                   @ 45,072,384 (3,072 B)
// part : f32  [512]                   @ 45,075,456 (2,048 B)
// dmin : f32  [32]                    @ 45,077,504 (128 B)

__device__ __forceinline__ void async_copy16(const void* gsrc, void* ldst) {
    __builtin_amdgcn_global_load_lds(
        (const __attribute__((address_space(1))) void*)gsrc,
        (__attribute__((address_space(3))) void*)ldst,
        16, 0, 0);
}

__device__ __forceinline__ unsigned short f2bf(float f) {  // RNE, matches __float2bfloat16
    unsigned u = __float_as_uint(f);
    u += 0x7FFFu + ((u >> 16) & 1u);
    return (unsigned short)(u >> 16);
}

// -------- per-batch min (two stage) --------
__global__ __launch_bounds__(256) void min_partial_kernel(const float* __restrict__ x,
                                                          float* __restrict__ partial) {
    const int blk = blockIdx.x;           // 512 blocks: 32 batches x 16 chunks
    const int b = blk >> 4, c = blk & 15;
    const float4* p = (const float4*)(x + (size_t)b * 262144 + (size_t)c * 16384);
    float mn = 3.0e38f;
    for (int i = threadIdx.x; i < 4096; i += 256) {
        float4 v = p[i];
        mn = fminf(mn, fminf(fminf(v.x, v.y), fminf(v.z, v.w)));
    }
    #pragma unroll
    for (int off = 32; off > 0; off >>= 1)
        mn = fminf(mn, __shfl_down(mn, off));
    __shared__ float red[4];
    if ((threadIdx.x & 63) == 0) red[threadIdx.x >> 6] = mn;
    __syncthreads();
    if (threadIdx.x == 0)
        partial[blk] = fminf(fminf(red[0], red[1]), fminf(red[2], red[3]));
}

__global__ void min_final_kernel(const float* __restrict__ partial, float* __restrict__ dmin) {
    const int t = threadIdx.x;
    if (t < 32) {
        float mn = 3.0e38f;
        for (int i = 0; i < 16; ++i) mn = fminf(mn, partial[t * 16 + i]);
        dmin[t] = mn;
    }
}

// -------- weight repack: W2[e][k] bf16, k = [g16 dh|g16 mp|g8 dh|g8 mp|g4 dh|g4 mp] --------
__global__ __launch_bounds__(256) void prep_kernel(const float* __restrict__ w0, const float* __restrict__ b0,
                                                   const float* __restrict__ w1, const float* __restrict__ b1,
                                                   const float* __restrict__ w2, const float* __restrict__ b2,
                                                   __hip_bfloat16* __restrict__ W2, float* __restrict__ biasT) {
    const int idx = blockIdx.x * 256 + threadIdx.x;
    if (idx < 768 * 672) {
        const int e = idx / 672, k = idx - e * 672;
        float v;
        if (k < 512)      v = w0[e * 512 + k];          // (2,16,16) flat
        else if (k < 640) v = w1[e * 128 + (k - 512)];  // (2,8,8) flat
        else              v = w2[e * 32  + (k - 640)];  // (2,4,4) flat
        W2[idx] = __float2bfloat16(v);
    }
    if (idx < 768) biasT[idx] = b0[idx] + b1[idx] + b2[idx];
}

// -------- per-patch: PURE REGISTER, one wave per patch, zero LDS (R8-proven) --------
__global__ __launch_bounds__(256) void patch_kernel(const float* __restrict__ x,
                                                    const float* __restrict__ dmin,
                                                    __hip_bfloat16* __restrict__ F,
                                                    float* __restrict__ maskout) {
    const int t = threadIdx.x;
    const int w = t >> 6, lane = t & 63;
    const int pid = blockIdx.x * 4 + w;       // wave = patch
    const int b = pid >> 10, n = pid & 1023;
    const int gi = n >> 5, gj = n & 31;
    const int row = lane >> 2, cq = lane & 3, cg = cq * 4;
    const float thr = dmin[b] + 1e-6f;

    const float4 v = *(const float4*)(x + ((size_t)(b * 512 + gi * 16 + row)) * 512 + gj * 16 + cg);
    float enc0, enc1, enc2, enc3;
    ushort4 om;
    {
        const bool v0 = v.x > thr, v1 = v.y > thr, v2 = v.z > thr, v3 = v.w > thr;
        enc0 = v0 ? fmaf(v.x, 0.99999000009999f, 256.0f) : 0.0f;   // 256 + d/1.00001
        enc1 = v1 ? fmaf(v.y, 0.99999000009999f, 256.0f) : 0.0f;
        enc2 = v2 ? fmaf(v.z, 0.99999000009999f, 256.0f) : 0.0f;
        enc3 = v3 ? fmaf(v.w, 0.99999000009999f, 256.0f) : 0.0f;
        om.x = v0 ? 0x3F80 : 0; om.y = v1 ? 0x3F80 : 0;            // bf16(1.0/0.0)
        om.z = v2 ? 0x3F80 : 0; om.w = v3 ? 0x3F80 : 0;
    }

    // ---- pools from initial encoded values (register butterflies) ----
    const float vs0 = enc0 + __shfl(enc0, lane ^ 4);   // vertical row-pair sums
    const float vs1 = enc1 + __shfl(enc1, lane ^ 4);
    const float vs2 = enc2 + __shfl(enc2, lane ^ 4);
    const float vs3 = enc3 + __shfl(enc3, lane ^ 4);
    const float a80 = vs0 + vs1, a81 = vs2 + vs3;      // g8 cells (row>>1,2cq),(row>>1,2cq+1)
    const int r8 = lane >> 3, c8 = lane & 7;
    const int src8 = r8 * 8 + (c8 >> 1);
    const float t80 = __shfl(a80, src8), t81 = __shfl(a81, src8);
    const float sum8 = (c8 & 1) ? t81 : t80;           // encoded 2x2 sum of my g8 cell
    const float N8 = floorf(sum8 * 0.00390625f);
    const float S8 = fmaf(N8, -256.0f, sum8);
    const float mp8 = N8 * 0.25f;
    const float dh8 = (S8 * 0.2500025f) / fmaf(N8, 0.25f, 1e-5f);  // (S/1.00001/4)/(mp8+1e-5)
    float enc8 = (N8 >= 1.0f) ? (256.0f + fmaxf(dh8, 0.0f)) : 0.0f;
    // g4 sums from g8 sums
    const float vp8 = sum8 + __shfl(sum8, lane ^ 8);
    const float sum4w = vp8 + __shfl(vp8, lane ^ 1);   // g4 cell (r8>>1,c8>>1), duplicated
    const int cell4 = lane & 15;
    const int r4 = cell4 >> 2, c4 = cell4 & 3;
    const float s4 = __shfl(sum4w, r4 * 16 + c4 * 2);
    const float N4 = floorf(s4 * 0.00390625f);
    const float S4 = fmaf(N4, -256.0f, s4);
    const float mp4 = N4 * 0.0625f;
    const float dh4 = (S4 * 0.062500625f) / fmaf(N4, 0.0625f, 1e-5f);
    float enc4 = (N4 >= 1.0f) ? (256.0f + fmaxf(dh4, 0.0f)) : 0.0f;

    // ---- g16 fill: 4 contiguous cells/lane, 14 shfls/iter, encode arithmetic ----
    {
        const float okT = (row > 0) ? 1.f : 0.f, okB = (row < 15) ? 1.f : 0.f;
        const float okL = (cq > 0) ? 1.f : 0.f, okR = (cq < 3) ? 1.f : 0.f;
        const float okTL = okT * okL, okTR = okT * okR, okBL = okB * okL, okBR = okB * okR;
        const int liU = (lane - 4) & 63, liD = (lane + 4) & 63;
        const int liL = (lane - 1) & 63, liR = (lane + 1) & 63;
        const int liUL = (lane - 5) & 63, liUR = (lane - 3) & 63;
        const int liDL = (lane + 3) & 63, liDR = (lane + 5) & 63;
        for (;;) {
            float u0 = __shfl(enc0, liU), u1 = __shfl(enc1, liU);
            float u2 = __shfl(enc2, liU), u3 = __shfl(enc3, liU);
            float b0_ = __shfl(enc0, liD), b1_ = __shfl(enc1, liD);
            float b2_ = __shfl(enc2, liD), b3_ = __shfl(enc3, liD);
            float eL  = __shfl(enc3, liL)  * okL;
            float eR  = __shfl(enc0, liR)  * okR;
            float eUL = __shfl(enc3, liUL) * okTL;
            float eUR = __shfl(enc0, liUR) * okTR;
            float eDL = __shfl(enc3, liDL) * okBL;
            float eDR = __shfl(enc0, liDR) * okBR;
            u0 *= okT; u1 *= okT; u2 *= okT; u3 *= okT;
            b0_ *= okB; b1_ *= okB; b2_ *= okB; b3_ *= okB;
            const float c0 = eUL + eL + eDL;
            const float c1 = u0 + enc0 + b0_;
            const float c2 = u1 + enc1 + b1_;
            const float c3 = u2 + enc2 + b2_;
            const float c4_ = u3 + enc3 + b3_;
            const float c5 = eUR + eR + eDR;
            float w0s = c0 + c1 + c2, w1s = c1 + c2 + c3;
            float w2s = c2 + c3 + c4_, w3s = c3 + c4_ + c5;
            asm volatile("" :: "v"(w0s), "v"(w1s), "v"(w2s), "v"(w3s));  // pin (uniform path)
            int fill = 0;
            if (enc0 < 256.f) {
                const float Nf = floorf(w0s * 0.00390625f);
                if (Nf >= 1.f) { enc0 = 256.f + fmaxf(fmaf(Nf, -256.f, w0s), 0.f) * __builtin_amdgcn_rcpf(Nf); fill = 1; }
            }
            if (enc1 < 256.f) {
                const float Nf = floorf(w1s * 0.00390625f);
                if (Nf >= 1.f) { enc1 = 256.f + fmaxf(fmaf(Nf, -256.f, w1s), 0.f) * __builtin_amdgcn_rcpf(Nf); fill = 1; }
            }
            if (enc2 < 256.f) {
                const float Nf = floorf(w2s * 0.00390625f);
                if (Nf >= 1.f) { enc2 = 256.f + fmaxf(fmaf(Nf, -256.f, w2s), 0.f) * __builtin_amdgcn_rcpf(Nf); fill = 1; }
            }
            if (enc3 < 256.f) {
                const float Nf = floorf(w3s * 0.00390625f);
                if (Nf >= 1.f) { enc3 = 256.f + fmaxf(fmaf(Nf, -256.f, w3s), 0.f) * __builtin_amdgcn_rcpf(Nf); fill = 1; }
            }
            if (!__any(fill)) break;
        }
    }
    unsigned short* Fp = (unsigned short*)(F + (size_t)pid * 672);
    {
        ushort4 o;
        o.x = f2bf(fmaxf(enc0 - 256.f, 0.f)); o.y = f2bf(fmaxf(enc1 - 256.f, 0.f));
        o.z = f2bf(fmaxf(enc2 - 256.f, 0.f)); o.w = f2bf(fmaxf(enc3 - 256.f, 0.f));
        const int co = row * 16 + cg;
        *(ushort4*)(Fp + co) = o;
        *(ushort4*)(Fp + 256 + co) = om;
    }

    // ---- g8 fill: encoded, unconditional shfl + post-masks ----
    {
        const float okU = (r8 > 0) ? 1.f : 0.f;
        const float okD = (r8 < 7) ? 1.f : 0.f;
        const float okL = (c8 > 0) ? 1.f : 0.f;
        const float okR = (c8 < 7) ? 1.f : 0.f;
        const float mUL = okU * okL, mUR = okU * okR, mDL = okD * okL, mDR = okD * okR;
        for (int it = 0; it < 8; ++it) {
            const float nU  = __shfl(enc8, (lane - 8) & 63);
            const float nD  = __shfl(enc8, (lane + 8) & 63);
            const float nL  = __shfl(enc8, (lane - 1) & 63);
            const float nR  = __shfl(enc8, (lane + 1) & 63);
            const float nUL = __shfl(enc8, (lane - 9) & 63);
            const float nUR = __shfl(enc8, (lane - 7) & 63);
            const float nDL = __shfl(enc8, (lane + 7) & 63);
            const float nDR = __shfl(enc8, (lane + 9) & 63);
            float s = (okU * nU + okD * nD) + (okL * nL + okR * nR)
                    + (mUL * nUL + mUR * nUR) + (mDL * nDL + mDR * nDR);
            asm volatile("" :: "v"(s));            // pin to uniform path
            int fill = 0;
            if (enc8 < 256.f) {
                const float Nf = floorf(s * 0.00390625f);
                if (Nf >= 1.f) { enc8 = 256.f + fmaxf(fmaf(Nf, -256.f, s), 0.f) * __builtin_amdgcn_rcpf(Nf); fill = 1; }
            }
            if (!__any(fill)) break;
        }
        Fp[512 + lane] = f2bf(fmaxf(enc8 - 256.f, 0.f));
        Fp[576 + lane] = f2bf(mp8);
    }

    // ---- g4 fill: encoded, 4x4 mirrored across lane groups ----
    {
        const float okU = (r4 > 0) ? 1.f : 0.f;
        const float okD = (r4 < 3) ? 1.f : 0.f;
        const float okL = (c4 > 0) ? 1.f : 0.f;
        const float okR = (c4 < 3) ? 1.f : 0.f;
        const float mUL = okU * okL, mUR = okU * okR, mDL = okD * okL, mDR = okD * okR;
        for (int it = 0; it < 4; ++it) {
            const float nU  = __shfl(enc4, (cell4 - 4) & 63);
            const float nD  = __shfl(enc4, (cell4 + 4) & 63);
            const float nL  = __shfl(enc4, (cell4 - 1) & 63);
            const float nR  = __shfl(enc4, (cell4 + 1) & 63);
            const float nUL = __shfl(enc4, (cell4 - 5) & 63);
            const float nUR = __shfl(enc4, (cell4 - 3) & 63);
            const float nDL = __shfl(enc4, (cell4 + 3) & 63);
            const float nDR = __shfl(enc4, (cell4 + 5) & 63);
            float s = (okU * nU + okD * nD) + (okL * nL + okR * nR)
                    + (mUL * nUL + mUR * nUR) + (mDL * nDL + mDR * nDR);
            asm volatile("" :: "v"(s));            // pin to uniform path
            int fill = 0;
            if (enc4 < 256.f) {
                const float Nf = floorf(s * 0.00390625f);
                if (Nf >= 1.f) { enc4 = 256.f + fmaxf(fmaf(Nf, -256.f, s), 0.f) * __builtin_amdgcn_rcpf(Nf); fill = 1; }
            }
            if (!__any(fill)) break;
        }
        if (lane < 16) {
            Fp[640 + lane] = f2bf(fmaxf(enc4 - 256.f, 0.f));
            Fp[656 + lane] = f2bf(mp4);
        }
        const unsigned long long bal = __ballot(lane < 16 && N4 >= 1.0f);
        if (lane == 0) maskout[pid] = bal ? 1.0f : 0.0f;
    }
}

// -------- GEMM: out[32768][768] = F[32768][672] @ W2[768][672]^T + biasT --------
// 128x128 tile, BK=32 (R6-proven loop), but 8 WAVES (512 threads): each wave
// owns a 64x32 sub-tile -> acc 32 regs (vs 64), ~85 regs/wave -> 2x occupancy
// for latency hiding. LDS 16 KB. XCD swizzle colocates same-tm tiles per XCD.
__global__ __launch_bounds__(512, 4) void gemm_kernel(const short* __restrict__ F,
                                                      const short* __restrict__ W2,
                                                      const float* __restrict__ biasT,
                                                      float* __restrict__ out) {
    constexpr int K = 672, N = 768;
    const int bid = blockIdx.x;                    // 1536 = 256 m-tiles x 6 n-tiles
    const int swz = (bid & 7) * 192 + (bid >> 3);  // bijective (1536 % 8 == 0)
    const int tm = swz / 6, tn = swz % 6;
    const int m0 = tm * 128, e0 = tn * 128;
    const int t = threadIdx.x;
    const int wave = t >> 6, lane = t & 63;        // 8 waves
    const int wm = wave >> 2, wn = wave & 3;       // 2x4 wave grid: 64x32 each
    const int lg = lane & 15, kc = lane >> 4;

    __shared__ short lds_a[4096];   // [kcc(4)][row(128)][8] = 8 KB
    __shared__ short lds_b[4096];

    // each wave stages one A slot + one B slot (8 slots each of 1 KB)
    const int skcc = wave >> 1, srow0 = (wave & 1) << 6;

    f32x4 acc[4][2];
    const f32x4 zero = {0.f, 0.f, 0.f, 0.f};
    #pragma unroll
    for (int i = 0; i < 4; ++i)
        #pragma unroll
        for (int j = 0; j < 2; ++j) acc[i][j] = zero;

    for (int kb = 0; kb < K; kb += 32) {
        __syncthreads();   // previous step's reads done before overwrite
        async_copy16(F  + (size_t)(m0 + srow0 + lane) * K + kb + skcc * 8,
                     &lds_a[(skcc * 128 + srow0) * 8]);
        async_copy16(W2 + (size_t)(e0 + srow0 + lane) * K + kb + skcc * 8,
                     &lds_b[(skcc * 128 + srow0) * 8]);
        __syncthreads();   // drain: staged data visible

        bf16x8 af[4], bfr[2];
        #pragma unroll
        for (int i = 0; i < 4; ++i)
            af[i]  = *(const bf16x8*)&lds_a[(kc * 128 + wm * 64 + i * 16 + lg) * 8];
        #pragma unroll
        for (int j = 0; j < 2; ++j)
            bfr[j] = *(const bf16x8*)&lds_b[(kc * 128 + wn * 32 + j * 16 + lg) * 8];
        #pragma unroll
        for (int i = 0; i < 4; ++i)
            #pragma unroll
            for (int j = 0; j < 2; ++j)
                acc[i][j] = __builtin_amdgcn_mfma_f32_16x16x32_bf16(af[i], bfr[j], acc[i][j], 0, 0, 0);
    }

    // epilogue: C/D layout col=lane&15, row=(lane>>4)*4+reg (m89-verified)
    const int rbase = (lane >> 4) * 4;
    #pragma unroll
    for (int j = 0; j < 2; ++j) {
        const int e = e0 + wn * 32 + j * 16 + lg;
        const float bs = biasT[e];
        #pragma unroll
        for (int i = 0; i < 4; ++i) {
            const int mr = m0 + wm * 64 + i * 16 + rbase;
            #pragma unroll
            for (int r = 0; r < 4; ++r)
                out[(size_t)(mr + r) * N + e] = acc[i][j][r] + bs;
        }
    }
}

extern "C" void kernel_launch(void* const* d_in, const int* in_sizes, int n_in,
                              void* d_out, int out_size, void* d_ws, size_t ws_size,
                              hipStream_t stream) {
    const float* x  = (const float*)d_in[0];
    const float* w0 = (const float*)d_in[1];
    const float* b0 = (const float*)d_in[2];
    const float* w1 = (const float*)d_in[3];
    const float* b1 = (const float*)d_in[4];
    const float* w2 = (const float*)d_in[5];
    const float* b2 = (const float*)d_in[6];
    float* out = (float*)d_out;

    char* ws = (char*)d_ws;
    __hip_bfloat16* F   = (__hip_bfloat16*)ws;
    __hip_bfloat16* W2  = (__hip_bfloat16*)(ws + 44040192);
    float* biasT        = (float*)(ws + 45072384);
    float* partial      = (float*)(ws + 45075456);
    float* dmin         = (float*)(ws + 45077504);
    float* maskout      = out + 25165824;   // feat is 32*1024*768

    min_partial_kernel<<<512, 256, 0, stream>>>(x, partial);
    min_final_kernel<<<1, 64, 0, stream>>>(partial, dmin);
    prep_kernel<<<2016, 256, 0, stream>>>(w0, b0, w1, b1, w2, b2, W2, biasT);
    patch_kernel<<<8192, 256, 0, stream>>>(x, dmin, F, maskout);
    gemm_kernel<<<1536, 512, 0, stream>>>((const short*)F, (const short*)W2, biasT, out);
}

// Round 11
// 129.309 us; speedup vs baseline: 1.1073x; 1.1073x over previous
//
#include <hip/hip_runtime.h>
#include <hip/hip_bf16.h>

typedef __attribute__((ext_vector_type(8))) short bf16x8;
typedef __attribute__((ext_vector_type(4))) float f32x4;

// ---------------- ws layout ----------------
// F    : bf16 [32768][672]            @ 0          (44,040,192 B)
// W2   : bf16 [768][672]              @ 44,040,192 (1,032,192 B)
// biasT: f32  [768]                   @ 45,072,384 (3,072 B)
// part : f32  [512]                   @ 45,075,456 (2,048 B)
// dmin : f32  [32]                    @ 45,077,504 (128 B)

__device__ __forceinline__ void async_copy16(const void* gsrc, void* ldst) {
    __builtin_amdgcn_global_load_lds(
        (const __attribute__((address_space(1))) void*)gsrc,
        (__attribute__((address_space(3))) void*)ldst,
        16, 0, 0);
}

__device__ __forceinline__ unsigned short f2bf(float f) {  // RNE, matches __float2bfloat16
    unsigned u = __float_as_uint(f);
    u += 0x7FFFu + ((u >> 16) & 1u);
    return (unsigned short)(u >> 16);
}

// -------- per-batch min (two stage) --------
__global__ __launch_bounds__(256) void min_partial_kernel(const float* __restrict__ x,
                                                          float* __restrict__ partial) {
    const int blk = blockIdx.x;           // 512 blocks: 32 batches x 16 chunks
    const int b = blk >> 4, c = blk & 15;
    const float4* p = (const float4*)(x + (size_t)b * 262144 + (size_t)c * 16384);
    float mn = 3.0e38f;
    for (int i = threadIdx.x; i < 4096; i += 256) {
        float4 v = p[i];
        mn = fminf(mn, fminf(fminf(v.x, v.y), fminf(v.z, v.w)));
    }
    #pragma unroll
    for (int off = 32; off > 0; off >>= 1)
        mn = fminf(mn, __shfl_down(mn, off));
    __shared__ float red[4];
    if ((threadIdx.x & 63) == 0) red[threadIdx.x >> 6] = mn;
    __syncthreads();
    if (threadIdx.x == 0)
        partial[blk] = fminf(fminf(red[0], red[1]), fminf(red[2], red[3]));
}

__global__ void min_final_kernel(const float* __restrict__ partial, float* __restrict__ dmin) {
    const int t = threadIdx.x;
    if (t < 32) {
        float mn = 3.0e38f;
        for (int i = 0; i < 16; ++i) mn = fminf(mn, partial[t * 16 + i]);
        dmin[t] = mn;
    }
}

// -------- weight repack: W2[e][k] bf16, k = [g16 dh|g16 mp|g8 dh|g8 mp|g4 dh|g4 mp] --------
__global__ __launch_bounds__(256) void prep_kernel(const float* __restrict__ w0, const float* __restrict__ b0,
                                                   const float* __restrict__ w1, const float* __restrict__ b1,
                                                   const float* __restrict__ w2, const float* __restrict__ b2,
                                                   __hip_bfloat16* __restrict__ W2, float* __restrict__ biasT) {
    const int idx = blockIdx.x * 256 + threadIdx.x;
    if (idx < 768 * 672) {
        const int e = idx / 672, k = idx - e * 672;
        float v;
        if (k < 512)      v = w0[e * 512 + k];          // (2,16,16) flat
        else if (k < 640) v = w1[e * 128 + (k - 512)];  // (2,8,8) flat
        else              v = w2[e * 32  + (k - 640)];  // (2,4,4) flat
        W2[idx] = __float2bfloat16(v);
    }
    if (idx < 768) biasT[idx] = b0[idx] + b1[idx] + b2[idx];
}

// -------- per-patch: PURE REGISTER, one wave per patch, zero LDS (R8/R9-proven) --------
__global__ __launch_bounds__(256) void patch_kernel(const float* __restrict__ x,
                                                    const float* __restrict__ dmin,
                                                    __hip_bfloat16* __restrict__ F,
                                                    float* __restrict__ maskout) {
    const int t = threadIdx.x;
    const int w = t >> 6, lane = t & 63;
    const int pid = blockIdx.x * 4 + w;       // wave = patch
    const int b = pid >> 10, n = pid & 1023;
    const int gi = n >> 5, gj = n & 31;
    const int row = lane >> 2, cq = lane & 3, cg = cq * 4;
    const float thr = dmin[b] + 1e-6f;

    const float4 v = *(const float4*)(x + ((size_t)(b * 512 + gi * 16 + row)) * 512 + gj * 16 + cg);
    float enc0, enc1, enc2, enc3;
    ushort4 om;
    {
        const bool v0 = v.x > thr, v1 = v.y > thr, v2 = v.z > thr, v3 = v.w > thr;
        enc0 = v0 ? fmaf(v.x, 0.99999000009999f, 256.0f) : 0.0f;   // 256 + d/1.00001
        enc1 = v1 ? fmaf(v.y, 0.99999000009999f, 256.0f) : 0.0f;
        enc2 = v2 ? fmaf(v.z, 0.99999000009999f, 256.0f) : 0.0f;
        enc3 = v3 ? fmaf(v.w, 0.99999000009999f, 256.0f) : 0.0f;
        om.x = v0 ? 0x3F80 : 0; om.y = v1 ? 0x3F80 : 0;            // bf16(1.0/0.0)
        om.z = v2 ? 0x3F80 : 0; om.w = v3 ? 0x3F80 : 0;
    }

    // ---- pools from initial encoded values (register butterflies) ----
    const float vs0 = enc0 + __shfl(enc0, lane ^ 4);   // vertical row-pair sums
    const float vs1 = enc1 + __shfl(enc1, lane ^ 4);
    const float vs2 = enc2 + __shfl(enc2, lane ^ 4);
    const float vs3 = enc3 + __shfl(enc3, lane ^ 4);
    const float a80 = vs0 + vs1, a81 = vs2 + vs3;      // g8 cells (row>>1,2cq),(row>>1,2cq+1)
    const int r8 = lane >> 3, c8 = lane & 7;
    const int src8 = r8 * 8 + (c8 >> 1);
    const float t80 = __shfl(a80, src8), t81 = __shfl(a81, src8);
    const float sum8 = (c8 & 1) ? t81 : t80;           // encoded 2x2 sum of my g8 cell
    const float N8 = floorf(sum8 * 0.00390625f);
    const float S8 = fmaf(N8, -256.0f, sum8);
    const float mp8 = N8 * 0.25f;
    const float dh8 = (S8 * 0.2500025f) / fmaf(N8, 0.25f, 1e-5f);  // (S/1.00001/4)/(mp8+1e-5)
    float enc8 = (N8 >= 1.0f) ? (256.0f + fmaxf(dh8, 0.0f)) : 0.0f;
    // g4 sums from g8 sums
    const float vp8 = sum8 + __shfl(sum8, lane ^ 8);
    const float sum4w = vp8 + __shfl(vp8, lane ^ 1);   // g4 cell (r8>>1,c8>>1), duplicated
    const int cell4 = lane & 15;
    const int r4 = cell4 >> 2, c4 = cell4 & 3;
    const float s4 = __shfl(sum4w, r4 * 16 + c4 * 2);
    const float N4 = floorf(s4 * 0.00390625f);
    const float S4 = fmaf(N4, -256.0f, s4);
    const float mp4 = N4 * 0.0625f;
    const float dh4 = (S4 * 0.062500625f) / fmaf(N4, 0.0625f, 1e-5f);
    float enc4 = (N4 >= 1.0f) ? (256.0f + fmaxf(dh4, 0.0f)) : 0.0f;

    // ---- g16 fill: 4 contiguous cells/lane, 14 shfls/iter, encode arithmetic ----
    {
        const float okT = (row > 0) ? 1.f : 0.f, okB = (row < 15) ? 1.f : 0.f;
        const float okL = (cq > 0) ? 1.f : 0.f, okR = (cq < 3) ? 1.f : 0.f;
        const float okTL = okT * okL, okTR = okT * okR, okBL = okB * okL, okBR = okB * okR;
        const int liU = (lane - 4) & 63, liD = (lane + 4) & 63;
        const int liL = (lane - 1) & 63, liR = (lane + 1) & 63;
        const int liUL = (lane - 5) & 63, liUR = (lane - 3) & 63;
        const int liDL = (lane + 3) & 63, liDR = (lane + 5) & 63;
        for (;;) {
            float u0 = __shfl(enc0, liU), u1 = __shfl(enc1, liU);
            float u2 = __shfl(enc2, liU), u3 = __shfl(enc3, liU);
            float b0_ = __shfl(enc0, liD), b1_ = __shfl(enc1, liD);
            float b2_ = __shfl(enc2, liD), b3_ = __shfl(enc3, liD);
            float eL  = __shfl(enc3, liL)  * okL;
            float eR  = __shfl(enc0, liR)  * okR;
            float eUL = __shfl(enc3, liUL) * okTL;
            float eUR = __shfl(enc0, liUR) * okTR;
            float eDL = __shfl(enc3, liDL) * okBL;
            float eDR = __shfl(enc0, liDR) * okBR;
            u0 *= okT; u1 *= okT; u2 *= okT; u3 *= okT;
            b0_ *= okB; b1_ *= okB; b2_ *= okB; b3_ *= okB;
            const float c0 = eUL + eL + eDL;
            const float c1 = u0 + enc0 + b0_;
            const float c2 = u1 + enc1 + b1_;
            const float c3 = u2 + enc2 + b2_;
            const float c4_ = u3 + enc3 + b3_;
            const float c5 = eUR + eR + eDR;
            float w0s = c0 + c1 + c2, w1s = c1 + c2 + c3;
            float w2s = c2 + c3 + c4_, w3s = c3 + c4_ + c5;
            asm volatile("" :: "v"(w0s), "v"(w1s), "v"(w2s), "v"(w3s));  // pin (uniform path)
            int fill = 0;
            if (enc0 < 256.f) {
                const float Nf = floorf(w0s * 0.00390625f);
                if (Nf >= 1.f) { enc0 = 256.f + fmaxf(fmaf(Nf, -256.f, w0s), 0.f) * __builtin_amdgcn_rcpf(Nf); fill = 1; }
            }
            if (enc1 < 256.f) {
                const float Nf = floorf(w1s * 0.00390625f);
                if (Nf >= 1.f) { enc1 = 256.f + fmaxf(fmaf(Nf, -256.f, w1s), 0.f) * __builtin_amdgcn_rcpf(Nf); fill = 1; }
            }
            if (enc2 < 256.f) {
                const float Nf = floorf(w2s * 0.00390625f);
                if (Nf >= 1.f) { enc2 = 256.f + fmaxf(fmaf(Nf, -256.f, w2s), 0.f) * __builtin_amdgcn_rcpf(Nf); fill = 1; }
            }
            if (enc3 < 256.f) {
                const float Nf = floorf(w3s * 0.00390625f);
                if (Nf >= 1.f) { enc3 = 256.f + fmaxf(fmaf(Nf, -256.f, w3s), 0.f) * __builtin_amdgcn_rcpf(Nf); fill = 1; }
            }
            if (!__any(fill)) break;
        }
    }
    unsigned short* Fp = (unsigned short*)(F + (size_t)pid * 672);
    {
        ushort4 o;
        o.x = f2bf(fmaxf(enc0 - 256.f, 0.f)); o.y = f2bf(fmaxf(enc1 - 256.f, 0.f));
        o.z = f2bf(fmaxf(enc2 - 256.f, 0.f)); o.w = f2bf(fmaxf(enc3 - 256.f, 0.f));
        const int co = row * 16 + cg;
        *(ushort4*)(Fp + co) = o;
        *(ushort4*)(Fp + 256 + co) = om;
    }

    // ---- g8 fill: encoded, unconditional shfl + post-masks ----
    {
        const float okU = (r8 > 0) ? 1.f : 0.f;
        const float okD = (r8 < 7) ? 1.f : 0.f;
        const float okL = (c8 > 0) ? 1.f : 0.f;
        const float okR = (c8 < 7) ? 1.f : 0.f;
        const float mUL = okU * okL, mUR = okU * okR, mDL = okD * okL, mDR = okD * okR;
        for (int it = 0; it < 8; ++it) {
            const float nU  = __shfl(enc8, (lane - 8) & 63);
            const float nD  = __shfl(enc8, (lane + 8) & 63);
            const float nL  = __shfl(enc8, (lane - 1) & 63);
            const float nR  = __shfl(enc8, (lane + 1) & 63);
            const float nUL = __shfl(enc8, (lane - 9) & 63);
            const float nUR = __shfl(enc8, (lane - 7) & 63);
            const float nDL = __shfl(enc8, (lane + 7) & 63);
            const float nDR = __shfl(enc8, (lane + 9) & 63);
            float s = (okU * nU + okD * nD) + (okL * nL + okR * nR)
                    + (mUL * nUL + mUR * nUR) + (mDL * nDL + mDR * nDR);
            asm volatile("" :: "v"(s));            // pin to uniform path
            int fill = 0;
            if (enc8 < 256.f) {
                const float Nf = floorf(s * 0.00390625f);
                if (Nf >= 1.f) { enc8 = 256.f + fmaxf(fmaf(Nf, -256.f, s), 0.f) * __builtin_amdgcn_rcpf(Nf); fill = 1; }
            }
            if (!__any(fill)) break;
        }
        Fp[512 + lane] = f2bf(fmaxf(enc8 - 256.f, 0.f));
        Fp[576 + lane] = f2bf(mp8);
    }

    // ---- g4 fill: encoded, 4x4 mirrored across lane groups ----
    {
        const float okU = (r4 > 0) ? 1.f : 0.f;
        const float okD = (r4 < 3) ? 1.f : 0.f;
        const float okL = (c4 > 0) ? 1.f : 0.f;
        const float okR = (c4 < 3) ? 1.f : 0.f;
        const float mUL = okU * okL, mUR = okU * okR, mDL = okD * okL, mDR = okD * okR;
        for (int it = 0; it < 4; ++it) {
            const float nU  = __shfl(enc4, (cell4 - 4) & 63);
            const float nD  = __shfl(enc4, (cell4 + 4) & 63);
            const float nL  = __shfl(enc4, (cell4 - 1) & 63);
            const float nR  = __shfl(enc4, (cell4 + 1) & 63);
            const float nUL = __shfl(enc4, (cell4 - 5) & 63);
            const float nUR = __shfl(enc4, (cell4 - 3) & 63);
            const float nDL = __shfl(enc4, (cell4 + 3) & 63);
            const float nDR = __shfl(enc4, (cell4 + 5) & 63);
            float s = (okU * nU + okD * nD) + (okL * nL + okR * nR)
                    + (mUL * nUL + mUR * nUR) + (mDL * nDL + mDR * nDR);
            asm volatile("" :: "v"(s));            // pin to uniform path
            int fill = 0;
            if (enc4 < 256.f) {
                const float Nf = floorf(s * 0.00390625f);
                if (Nf >= 1.f) { enc4 = 256.f + fmaxf(fmaf(Nf, -256.f, s), 0.f) * __builtin_amdgcn_rcpf(Nf); fill = 1; }
            }
            if (!__any(fill)) break;
        }
        if (lane < 16) {
            Fp[640 + lane] = f2bf(fmaxf(enc4 - 256.f, 0.f));
            Fp[656 + lane] = f2bf(mp4);
        }
        const unsigned long long bal = __ballot(lane < 16 && N4 >= 1.0f);
        if (lane == 0) maskout[pid] = bal ? 1.0f : 0.0f;
    }
}

// -------- GEMM: out[32768][768] = F[32768][672] @ W2[768][672]^T + biasT --------
// R6 structure (128x128 tile, BK=32, 4 waves, 16 KB LDS, XCD swizzle) with an
// EXPLICIT vmcnt/lgkm drain before the publish barrier: correctness must not
// depend on hipcc's __syncthreads lowering draining vmcnt for global_load_lds
// (R10 post-timing divergence = flaky staging-visibility race).
__global__ __launch_bounds__(256) void gemm_kernel(const short* __restrict__ F,
                                                   const short* __restrict__ W2,
                                                   const float* __restrict__ biasT,
                                                   float* __restrict__ out) {
    constexpr int K = 672, N = 768;
    const int bid = blockIdx.x;                    // 1536 = 256 m-tiles x 6 n-tiles
    const int swz = (bid & 7) * 192 + (bid >> 3);  // bijective (1536 % 8 == 0)
    const int tm = swz / 6, tn = swz % 6;
    const int m0 = tm * 128, e0 = tn * 128;
    const int t = threadIdx.x;
    const int wave = t >> 6, lane = t & 63;
    const int wm = wave >> 1, wn = wave & 1;
    const int lg = lane & 15, kc = lane >> 4;

    __shared__ short lds_a[4096];   // [4][128][8]
    __shared__ short lds_b[4096];

    f32x4 acc[4][4];
    const f32x4 zero = {0.f, 0.f, 0.f, 0.f};
    #pragma unroll
    for (int i = 0; i < 4; ++i)
        #pragma unroll
        for (int j = 0; j < 4; ++j) acc[i][j] = zero;

    for (int kb = 0; kb < K; kb += 32) {
        __syncthreads();   // all waves' LDS reads of prev tile complete
        #pragma unroll
        for (int si = 0; si < 2; ++si) {
            const int s = wave * 2 + si;
            const int row = ((s & 1) << 6) + lane;
            const int kcc = s >> 1;
            async_copy16(F  + (size_t)(m0 + row) * K + kb + kcc * 8, &lds_a[s * 512]);
            async_copy16(W2 + (size_t)(e0 + row) * K + kb + kcc * 8, &lds_b[s * 512]);
        }
        asm volatile("s_waitcnt vmcnt(0) lgkmcnt(0)" ::: "memory");  // explicit DMA drain
        __syncthreads();   // publish staged tile to all waves

        bf16x8 af[4], bfr[4];
        #pragma unroll
        for (int i = 0; i < 4; ++i) {
            af[i]  = *(const bf16x8*)&lds_a[(kc * 128 + wm * 64 + i * 16 + lg) * 8];
            bfr[i] = *(const bf16x8*)&lds_b[(kc * 128 + wn * 64 + i * 16 + lg) * 8];
        }
        #pragma unroll
        for (int i = 0; i < 4; ++i)
            #pragma unroll
            for (int j = 0; j < 4; ++j)
                acc[i][j] = __builtin_amdgcn_mfma_f32_16x16x32_bf16(af[i], bfr[j], acc[i][j], 0, 0, 0);
    }

    // epilogue: C/D layout col=lane&15, row=(lane>>4)*4+reg (m89-verified)
    const int rbase = (lane >> 4) * 4;
    #pragma unroll
    for (int j = 0; j < 4; ++j) {
        const int e = e0 + wn * 64 + j * 16 + lg;
        const float bs = biasT[e];
        #pragma unroll
        for (int i = 0; i < 4; ++i) {
            const int mr = m0 + wm * 64 + i * 16 + rbase;
            #pragma unroll
            for (int r = 0; r < 4; ++r)
                out[(size_t)(mr + r) * N + e] = acc[i][j][r] + bs;
        }
    }
}

extern "C" void kernel_launch(void* const* d_in, const int* in_sizes, int n_in,
                              void* d_out, int out_size, void* d_ws, size_t ws_size,
                              hipStream_t stream) {
    const float* x  = (const float*)d_in[0];
    const float* w0 = (const float*)d_in[1];
    const float* b0 = (const float*)d_in[2];
    const float* w1 = (const float*)d_in[3];
    const float* b1 = (const float*)d_in[4];
    const float* w2 = (const float*)d_in[5];
    const float* b2 = (const float*)d_in[6];
    float* out = (float*)d_out;

    char* ws = (char*)d_ws;
    __hip_bfloat16* F   = (__hip_bfloat16*)ws;
    __hip_bfloat16* W2  = (__hip_bfloat16*)(ws + 44040192);
    float* biasT        = (float*)(ws + 45072384);
    float* partial      = (float*)(ws + 45075456);
    float* dmin         = (float*)(ws + 45077504);
    float* maskout      = out + 25165824;   // feat is 32*1024*768

    min_partial_kernel<<<512, 256, 0, stream>>>(x, partial);
    min_final_kernel<<<1, 64, 0, stream>>>(partial, dmin);
    prep_kernel<<<2016, 256, 0, stream>>>(w0, b0, w1, b1, w2, b2, W2, biasT);
    patch_kernel<<<8192, 256, 0, stream>>>(x, dmin, F, maskout);
    gemm_kernel<<<1536, 256, 0, stream>>>((const short*)F, (const short*)W2, biasT, out);
}

// Round 12
// 117.467 us; speedup vs baseline: 1.2189x; 1.1008x over previous
//
#include <hip/hip_runtime.h>
#include <hip/hip_bf16.h>

typedef __attribute__((ext_vector_type(8))) short bf16x8;
typedef __attribute__((ext_vector_type(4))) float f32x4;

// ---------------- ws layout ----------------
// F'   : bf16 blocked [256 mtiles][84 kchunks][128 rows][8]  @ 0  (44,040,192 B)
//        element (pid,k) -> ((pid>>7)*84 + (k>>3))*1024 + (pid&127)*8 + (k&7)
// W2'  : bf16 blocked [6 etiles][84][128][8]  @ 44,040,192   (1,032,192 B)
// biasT: f32  [768]                   @ 45,072,384 (3,072 B)
// part : f32  [512]                   @ 45,075,456 (2,048 B)
// dmin : f32  [32]                    @ 45,077,504 (128 B)

__device__ __forceinline__ void async_copy16(const void* gsrc, void* ldst) {
    __builtin_amdgcn_global_load_lds(
        (const __attribute__((address_space(1))) void*)gsrc,
        (__attribute__((address_space(3))) void*)ldst,
        16, 0, 0);
}

__device__ __forceinline__ unsigned short f2bf(float f) {  // RNE, matches __float2bfloat16
    unsigned u = __float_as_uint(f);
    u += 0x7FFFu + ((u >> 16) & 1u);
    return (unsigned short)(u >> 16);
}

// -------- per-batch min (two stage) --------
__global__ __launch_bounds__(256) void min_partial_kernel(const float* __restrict__ x,
                                                          float* __restrict__ partial) {
    const int blk = blockIdx.x;           // 512 blocks: 32 batches x 16 chunks
    const int b = blk >> 4, c = blk & 15;
    const float4* p = (const float4*)(x + (size_t)b * 262144 + (size_t)c * 16384);
    float mn = 3.0e38f;
    for (int i = threadIdx.x; i < 4096; i += 256) {
        float4 v = p[i];
        mn = fminf(mn, fminf(fminf(v.x, v.y), fminf(v.z, v.w)));
    }
    #pragma unroll
    for (int off = 32; off > 0; off >>= 1)
        mn = fminf(mn, __shfl_down(mn, off));
    __shared__ float red[4];
    if ((threadIdx.x & 63) == 0) red[threadIdx.x >> 6] = mn;
    __syncthreads();
    if (threadIdx.x == 0)
        partial[blk] = fminf(fminf(red[0], red[1]), fminf(red[2], red[3]));
}

__global__ void min_final_kernel(const float* __restrict__ partial, float* __restrict__ dmin) {
    const int t = threadIdx.x;
    if (t < 32) {
        float mn = 3.0e38f;
        for (int i = 0; i < 16; ++i) mn = fminf(mn, partial[t * 16 + i]);
        dmin[t] = mn;
    }
}

// -------- weight repack into blocked K-major layout --------
__global__ __launch_bounds__(256) void prep_kernel(const float* __restrict__ w0, const float* __restrict__ b0,
                                                   const float* __restrict__ w1, const float* __restrict__ b1,
                                                   const float* __restrict__ w2, const float* __restrict__ b2,
                                                   __hip_bfloat16* __restrict__ W2, float* __restrict__ biasT) {
    const int idx = blockIdx.x * 256 + threadIdx.x;
    if (idx < 768 * 672) {
        const int e = idx / 672, k = idx - e * 672;
        float v;
        if (k < 512)      v = w0[e * 512 + k];          // (2,16,16) flat
        else if (k < 640) v = w1[e * 128 + (k - 512)];  // (2,8,8) flat
        else              v = w2[e * 32  + (k - 640)];  // (2,4,4) flat
        const int dst = ((e >> 7) * 84 + (k >> 3)) * 1024 + (e & 127) * 8 + (k & 7);
        W2[dst] = __float2bfloat16(v);
    }
    if (idx < 768) biasT[idx] = b0[idx] + b1[idx] + b2[idx];
}

// -------- per-patch: PURE REGISTER, one wave per patch, zero LDS (R11-proven math);
//          emits F in the blocked K-major layout --------
__global__ __launch_bounds__(256) void patch_kernel(const float* __restrict__ x,
                                                    const float* __restrict__ dmin,
                                                    __hip_bfloat16* __restrict__ F,
                                                    float* __restrict__ maskout) {
    const int t = threadIdx.x;
    const int w = t >> 6, lane = t & 63;
    const int pid = blockIdx.x * 4 + w;       // wave = patch
    const int b = pid >> 10, n = pid & 1023;
    const int gi = n >> 5, gj = n & 31;
    const int row = lane >> 2, cq = lane & 3, cg = cq * 4;
    const float thr = dmin[b] + 1e-6f;

    const float4 v = *(const float4*)(x + ((size_t)(b * 512 + gi * 16 + row)) * 512 + gj * 16 + cg);
    float enc0, enc1, enc2, enc3;
    ushort4 om;
    {
        const bool v0 = v.x > thr, v1 = v.y > thr, v2 = v.z > thr, v3 = v.w > thr;
        enc0 = v0 ? fmaf(v.x, 0.99999000009999f, 256.0f) : 0.0f;   // 256 + d/1.00001
        enc1 = v1 ? fmaf(v.y, 0.99999000009999f, 256.0f) : 0.0f;
        enc2 = v2 ? fmaf(v.z, 0.99999000009999f, 256.0f) : 0.0f;
        enc3 = v3 ? fmaf(v.w, 0.99999000009999f, 256.0f) : 0.0f;
        om.x = v0 ? 0x3F80 : 0; om.y = v1 ? 0x3F80 : 0;            // bf16(1.0/0.0)
        om.z = v2 ? 0x3F80 : 0; om.w = v3 ? 0x3F80 : 0;
    }

    // ---- pools from initial encoded values (register butterflies) ----
    const float vs0 = enc0 + __shfl(enc0, lane ^ 4);   // vertical row-pair sums
    const float vs1 = enc1 + __shfl(enc1, lane ^ 4);
    const float vs2 = enc2 + __shfl(enc2, lane ^ 4);
    const float vs3 = enc3 + __shfl(enc3, lane ^ 4);
    const float a80 = vs0 + vs1, a81 = vs2 + vs3;      // g8 cells (row>>1,2cq),(row>>1,2cq+1)
    const int r8 = lane >> 3, c8 = lane & 7;
    const int src8 = r8 * 8 + (c8 >> 1);
    const float t80 = __shfl(a80, src8), t81 = __shfl(a81, src8);
    const float sum8 = (c8 & 1) ? t81 : t80;           // encoded 2x2 sum of my g8 cell
    const float N8 = floorf(sum8 * 0.00390625f);
    const float S8 = fmaf(N8, -256.0f, sum8);
    const float mp8 = N8 * 0.25f;
    const float dh8 = (S8 * 0.2500025f) / fmaf(N8, 0.25f, 1e-5f);  // (S/1.00001/4)/(mp8+1e-5)
    float enc8 = (N8 >= 1.0f) ? (256.0f + fmaxf(dh8, 0.0f)) : 0.0f;
    // g4 sums from g8 sums
    const float vp8 = sum8 + __shfl(sum8, lane ^ 8);
    const float sum4w = vp8 + __shfl(vp8, lane ^ 1);   // g4 cell (r8>>1,c8>>1), duplicated
    const int cell4 = lane & 15;
    const int r4 = cell4 >> 2, c4 = cell4 & 3;
    const float s4 = __shfl(sum4w, r4 * 16 + c4 * 2);
    const float N4 = floorf(s4 * 0.00390625f);
    const float S4 = fmaf(N4, -256.0f, s4);
    const float mp4 = N4 * 0.0625f;
    const float dh4 = (S4 * 0.062500625f) / fmaf(N4, 0.0625f, 1e-5f);
    float enc4 = (N4 >= 1.0f) ? (256.0f + fmaxf(dh4, 0.0f)) : 0.0f;

    // ---- g16 fill: 4 contiguous cells/lane, 14 shfls/iter, encode arithmetic ----
    {
        const float okT = (row > 0) ? 1.f : 0.f, okB = (row < 15) ? 1.f : 0.f;
        const float okL = (cq > 0) ? 1.f : 0.f, okR = (cq < 3) ? 1.f : 0.f;
        const float okTL = okT * okL, okTR = okT * okR, okBL = okB * okL, okBR = okB * okR;
        const int liU = (lane - 4) & 63, liD = (lane + 4) & 63;
        const int liL = (lane - 1) & 63, liR = (lane + 1) & 63;
        const int liUL = (lane - 5) & 63, liUR = (lane - 3) & 63;
        const int liDL = (lane + 3) & 63, liDR = (lane + 5) & 63;
        for (;;) {
            float u0 = __shfl(enc0, liU), u1 = __shfl(enc1, liU);
            float u2 = __shfl(enc2, liU), u3 = __shfl(enc3, liU);
            float b0_ = __shfl(enc0, liD), b1_ = __shfl(enc1, liD);
            float b2_ = __shfl(enc2, liD), b3_ = __shfl(enc3, liD);
            float eL  = __shfl(enc3, liL)  * okL;
            float eR  = __shfl(enc0, liR)  * okR;
            float eUL = __shfl(enc3, liUL) * okTL;
            float eUR = __shfl(enc0, liUR) * okTR;
            float eDL = __shfl(enc3, liDL) * okBL;
            float eDR = __shfl(enc0, liDR) * okBR;
            u0 *= okT; u1 *= okT; u2 *= okT; u3 *= okT;
            b0_ *= okB; b1_ *= okB; b2_ *= okB; b3_ *= okB;
            const float c0 = eUL + eL + eDL;
            const float c1 = u0 + enc0 + b0_;
            const float c2 = u1 + enc1 + b1_;
            const float c3 = u2 + enc2 + b2_;
            const float c4_ = u3 + enc3 + b3_;
            const float c5 = eUR + eR + eDR;
            float w0s = c0 + c1 + c2, w1s = c1 + c2 + c3;
            float w2s = c2 + c3 + c4_, w3s = c3 + c4_ + c5;
            asm volatile("" :: "v"(w0s), "v"(w1s), "v"(w2s), "v"(w3s));  // pin (uniform path)
            int fill = 0;
            if (enc0 < 256.f) {
                const float Nf = floorf(w0s * 0.00390625f);
                if (Nf >= 1.f) { enc0 = 256.f + fmaxf(fmaf(Nf, -256.f, w0s), 0.f) * __builtin_amdgcn_rcpf(Nf); fill = 1; }
            }
            if (enc1 < 256.f) {
                const float Nf = floorf(w1s * 0.00390625f);
                if (Nf >= 1.f) { enc1 = 256.f + fmaxf(fmaf(Nf, -256.f, w1s), 0.f) * __builtin_amdgcn_rcpf(Nf); fill = 1; }
            }
            if (enc2 < 256.f) {
                const float Nf = floorf(w2s * 0.00390625f);
                if (Nf >= 1.f) { enc2 = 256.f + fmaxf(fmaf(Nf, -256.f, w2s), 0.f) * __builtin_amdgcn_rcpf(Nf); fill = 1; }
            }
            if (enc3 < 256.f) {
                const float Nf = floorf(w3s * 0.00390625f);
                if (Nf >= 1.f) { enc3 = 256.f + fmaxf(fmaf(Nf, -256.f, w3s), 0.f) * __builtin_amdgcn_rcpf(Nf); fill = 1; }
            }
            if (!__any(fill)) break;
        }
    }
    // ---- emit into blocked layout: base = (mtile*84)*1024 + prow*8 ----
    unsigned short* Fb = (unsigned short*)F + ((size_t)(pid >> 7) * 84) * 1024 + (pid & 127) * 8;
    {
        ushort4 o;
        o.x = f2bf(fmaxf(enc0 - 256.f, 0.f)); o.y = f2bf(fmaxf(enc1 - 256.f, 0.f));
        o.z = f2bf(fmaxf(enc2 - 256.f, 0.f)); o.w = f2bf(fmaxf(enc3 - 256.f, 0.f));
        const int co = row * 16 + cg;
        *(ushort4*)(Fb + (co >> 3) * 1024 + (co & 7)) = o;                 // k = co
        *(ushort4*)(Fb + (32 + (co >> 3)) * 1024 + (co & 7)) = om;         // k = 256+co
    }

    // ---- g8 fill: encoded, unconditional shfl + post-masks ----
    {
        const float okU = (r8 > 0) ? 1.f : 0.f;
        const float okD = (r8 < 7) ? 1.f : 0.f;
        const float okL = (c8 > 0) ? 1.f : 0.f;
        const float okR = (c8 < 7) ? 1.f : 0.f;
        const float mUL = okU * okL, mUR = okU * okR, mDL = okD * okL, mDR = okD * okR;
        for (int it = 0; it < 8; ++it) {
            const float nU  = __shfl(enc8, (lane - 8) & 63);
            const float nD  = __shfl(enc8, (lane + 8) & 63);
            const float nL  = __shfl(enc8, (lane - 1) & 63);
            const float nR  = __shfl(enc8, (lane + 1) & 63);
            const float nUL = __shfl(enc8, (lane - 9) & 63);
            const float nUR = __shfl(enc8, (lane - 7) & 63);
            const float nDL = __shfl(enc8, (lane + 7) & 63);
            const float nDR = __shfl(enc8, (lane + 9) & 63);
            float s = (okU * nU + okD * nD) + (okL * nL + okR * nR)
                    + (mUL * nUL + mUR * nUR) + (mDL * nDL + mDR * nDR);
            asm volatile("" :: "v"(s));            // pin to uniform path
            int fill = 0;
            if (enc8 < 256.f) {
                const float Nf = floorf(s * 0.00390625f);
                if (Nf >= 1.f) { enc8 = 256.f + fmaxf(fmaf(Nf, -256.f, s), 0.f) * __builtin_amdgcn_rcpf(Nf); fill = 1; }
            }
            if (!__any(fill)) break;
        }
        Fb[(64 + (lane >> 3)) * 1024 + (lane & 7)] = f2bf(fmaxf(enc8 - 256.f, 0.f));  // k = 512+lane
        Fb[(72 + (lane >> 3)) * 1024 + (lane & 7)] = f2bf(mp8);                        // k = 576+lane
    }

    // ---- g4 fill: encoded, 4x4 mirrored across lane groups ----
    {
        const float okU = (r4 > 0) ? 1.f : 0.f;
        const float okD = (r4 < 3) ? 1.f : 0.f;
        const float okL = (c4 > 0) ? 1.f : 0.f;
        const float okR = (c4 < 3) ? 1.f : 0.f;
        const float mUL = okU * okL, mUR = okU * okR, mDL = okD * okL, mDR = okD * okR;
        for (int it = 0; it < 4; ++it) {
            const float nU  = __shfl(enc4, (cell4 - 4) & 63);
            const float nD  = __shfl(enc4, (cell4 + 4) & 63);
            const float nL  = __shfl(enc4, (cell4 - 1) & 63);
            const float nR  = __shfl(enc4, (cell4 + 1) & 63);
            const float nUL = __shfl(enc4, (cell4 - 5) & 63);
            const float nUR = __shfl(enc4, (cell4 - 3) & 63);
            const float nDL = __shfl(enc4, (cell4 + 3) & 63);
            const float nDR = __shfl(enc4, (cell4 + 5) & 63);
            float s = (okU * nU + okD * nD) + (okL * nL + okR * nR)
                    + (mUL * nUL + mUR * nUR) + (mDL * nDL + mDR * nDR);
            asm volatile("" :: "v"(s));            // pin to uniform path
            int fill = 0;
            if (enc4 < 256.f) {
                const float Nf = floorf(s * 0.00390625f);
                if (Nf >= 1.f) { enc4 = 256.f + fmaxf(fmaf(Nf, -256.f, s), 0.f) * __builtin_amdgcn_rcpf(Nf); fill = 1; }
            }
            if (!__any(fill)) break;
        }
        if (lane < 16) {
            Fb[(80 + (lane >> 3)) * 1024 + (lane & 7)] = f2bf(fmaxf(enc4 - 256.f, 0.f));      // k = 640+lane
            Fb[(82 + (lane >> 3)) * 1024 + (lane & 7)] = f2bf(mp4);                            // k = 656+lane
        }
        const unsigned long long bal = __ballot(lane < 16 && N4 >= 1.0f);
        if (lane == 0) maskout[pid] = bal ? 1.0f : 0.0f;
    }
}

// -------- GEMM: out[32768][768] = F @ W2^T + biasT, blocked K-major inputs --------
// R11 structure (128x128, BK=32, 4 waves, 16 KB LDS, XCD swizzle, explicit
// vmcnt drain) with CONTIGUOUS 1-KB staging reads: each global_load_lds now
// touches 8 cache lines instead of 64 (F'/W2' blocked layout).
__global__ __launch_bounds__(256) void gemm_kernel(const short* __restrict__ F,
                                                   const short* __restrict__ W2,
                                                   const float* __restrict__ biasT,
                                                   float* __restrict__ out) {
    constexpr int N = 768;
    const int bid = blockIdx.x;                    // 1536 = 256 m-tiles x 6 n-tiles
    const int swz = (bid & 7) * 192 + (bid >> 3);  // bijective (1536 % 8 == 0)
    const int tm = swz / 6, tn = swz % 6;
    const int m0 = tm * 128, e0 = tn * 128;
    const int t = threadIdx.x;
    const int wave = t >> 6, lane = t & 63;
    const int wm = wave >> 1, wn = wave & 1;
    const int lg = lane & 15, kc = lane >> 4;

    __shared__ short lds_a[4096];   // [4][128][8]
    __shared__ short lds_b[4096];

    const size_t abase = (size_t)tm * 84 * 1024;   // F' m-tile base (elements)
    const size_t bbase = (size_t)tn * 84 * 1024;   // W2' e-tile base

    f32x4 acc[4][4];
    const f32x4 zero = {0.f, 0.f, 0.f, 0.f};
    #pragma unroll
    for (int i = 0; i < 4; ++i)
        #pragma unroll
        for (int j = 0; j < 4; ++j) acc[i][j] = zero;

    for (int kb = 0; kb < 672; kb += 32) {
        const int kbc = kb >> 3;                   // global k-chunk of this K-step
        __syncthreads();   // all waves' LDS reads of prev tile complete
        #pragma unroll
        for (int si = 0; si < 2; ++si) {
            const int s = wave * 2 + si;           // 8 slots of 1 KB each
            const int kccl = s >> 1, half = s & 1;
            const int row = half * 64 + lane;      // per-lane: contiguous 16B each
            async_copy16(F  + abase + (size_t)(kbc + kccl) * 1024 + row * 8, &lds_a[s * 512]);
            async_copy16(W2 + bbase + (size_t)(kbc + kccl) * 1024 + row * 8, &lds_b[s * 512]);
        }
        asm volatile("s_waitcnt vmcnt(0) lgkmcnt(0)" ::: "memory");  // explicit DMA drain
        __syncthreads();   // publish staged tile to all waves

        bf16x8 af[4], bfr[4];
        #pragma unroll
        for (int i = 0; i < 4; ++i) {
            af[i]  = *(const bf16x8*)&lds_a[(kc * 128 + wm * 64 + i * 16 + lg) * 8];
            bfr[i] = *(const bf16x8*)&lds_b[(kc * 128 + wn * 64 + i * 16 + lg) * 8];
        }
        #pragma unroll
        for (int i = 0; i < 4; ++i)
            #pragma unroll
            for (int j = 0; j < 4; ++j)
                acc[i][j] = __builtin_amdgcn_mfma_f32_16x16x32_bf16(af[i], bfr[j], acc[i][j], 0, 0, 0);
    }

    // epilogue: C/D layout col=lane&15, row=(lane>>4)*4+reg (m89-verified)
    const int rbase = (lane >> 4) * 4;
    #pragma unroll
    for (int j = 0; j < 4; ++j) {
        const int e = e0 + wn * 64 + j * 16 + lg;
        const float bs = biasT[e];
        #pragma unroll
        for (int i = 0; i < 4; ++i) {
            const int mr = m0 + wm * 64 + i * 16 + rbase;
            #pragma unroll
            for (int r = 0; r < 4; ++r)
                out[(size_t)(mr + r) * N + e] = acc[i][j][r] + bs;
        }
    }
}

extern "C" void kernel_launch(void* const* d_in, const int* in_sizes, int n_in,
                              void* d_out, int out_size, void* d_ws, size_t ws_size,
                              hipStream_t stream) {
    const float* x  = (const float*)d_in[0];
    const float* w0 = (const float*)d_in[1];
    const float* b0 = (const float*)d_in[2];
    const float* w1 = (const float*)d_in[3];
    const float* b1 = (const float*)d_in[4];
    const float* w2 = (const float*)d_in[5];
    const float* b2 = (const float*)d_in[6];
    float* out = (float*)d_out;

    char* ws = (char*)d_ws;
    __hip_bfloat16* F   = (__hip_bfloat16*)ws;
    __hip_bfloat16* W2  = (__hip_bfloat16*)(ws + 44040192);
    float* biasT        = (float*)(ws + 45072384);
    float* partial      = (float*)(ws + 45075456);
    float* dmin         = (float*)(ws + 45077504);
    float* maskout      = out + 25165824;   // feat is 32*1024*768

    min_partial_kernel<<<512, 256, 0, stream>>>(x, partial);
    min_final_kernel<<<1, 64, 0, stream>>>(partial, dmin);
    prep_kernel<<<2016, 256, 0, stream>>>(w0, b0, w1, b1, w2, b2, W2, biasT);
    patch_kernel<<<8192, 256, 0, stream>>>(x, dmin, F, maskout);
    gemm_kernel<<<1536, 256, 0, stream>>>((const short*)F, (const short*)W2, biasT, out);
}

// Round 13
// 99.384 us; speedup vs baseline: 1.4407x; 1.1820x over previous
//
#include <hip/hip_runtime.h>
#include <hip/hip_bf16.h>

typedef __attribute__((ext_vector_type(8))) short bf16x8;
typedef __attribute__((ext_vector_type(4))) float f32x4;

// ---------------- ws layout ----------------
// F'   : bf16 blocked [256 mtiles][84 kchunks][128 rows][8]  @ 0  (44,040,192 B)
//        element (pid,k) -> ((pid>>7)*84 + (k>>3))*1024 + (pid&127)*8 + (k&7)
// W2'  : bf16 blocked [6 etiles][84][128][8]  @ 44,040,192   (1,032,192 B)
// biasT: f32  [768]                   @ 45,072,384 (3,072 B)
// part : f32  [512]                   @ 45,075,456 (2,048 B)
// dmin : f32  [32]                    @ 45,077,504 (128 B)

__device__ __forceinline__ void async_copy16(const void* gsrc, void* ldst) {
    __builtin_amdgcn_global_load_lds(
        (const __attribute__((address_space(1))) void*)gsrc,
        (__attribute__((address_space(3))) void*)ldst,
        16, 0, 0);
}

__device__ __forceinline__ unsigned short f2bf(float f) {  // RNE, matches __float2bfloat16
    unsigned u = __float_as_uint(f);
    u += 0x7FFFu + ((u >> 16) & 1u);
    return (unsigned short)(u >> 16);
}

// -------- per-batch min (two stage) --------
__global__ __launch_bounds__(256) void min_partial_kernel(const float* __restrict__ x,
                                                          float* __restrict__ partial) {
    const int blk = blockIdx.x;           // 512 blocks: 32 batches x 16 chunks
    const int b = blk >> 4, c = blk & 15;
    const float4* p = (const float4*)(x + (size_t)b * 262144 + (size_t)c * 16384);
    float mn = 3.0e38f;
    for (int i = threadIdx.x; i < 4096; i += 256) {
        float4 v = p[i];
        mn = fminf(mn, fminf(fminf(v.x, v.y), fminf(v.z, v.w)));
    }
    #pragma unroll
    for (int off = 32; off > 0; off >>= 1)
        mn = fminf(mn, __shfl_down(mn, off));
    __shared__ float red[4];
    if ((threadIdx.x & 63) == 0) red[threadIdx.x >> 6] = mn;
    __syncthreads();
    if (threadIdx.x == 0)
        partial[blk] = fminf(fminf(red[0], red[1]), fminf(red[2], red[3]));
}

__global__ void min_final_kernel(const float* __restrict__ partial, float* __restrict__ dmin) {
    const int t = threadIdx.x;
    if (t < 32) {
        float mn = 3.0e38f;
        for (int i = 0; i < 16; ++i) mn = fminf(mn, partial[t * 16 + i]);
        dmin[t] = mn;
    }
}

// -------- weight repack into blocked K-major layout --------
__global__ __launch_bounds__(256) void prep_kernel(const float* __restrict__ w0, const float* __restrict__ b0,
                                                   const float* __restrict__ w1, const float* __restrict__ b1,
                                                   const float* __restrict__ w2, const float* __restrict__ b2,
                                                   __hip_bfloat16* __restrict__ W2, float* __restrict__ biasT) {
    const int idx = blockIdx.x * 256 + threadIdx.x;
    if (idx < 768 * 672) {
        const int e = idx / 672, k = idx - e * 672;
        float v;
        if (k < 512)      v = w0[e * 512 + k];          // (2,16,16) flat
        else if (k < 640) v = w1[e * 128 + (k - 512)];  // (2,8,8) flat
        else              v = w2[e * 32  + (k - 640)];  // (2,4,4) flat
        const int dst = ((e >> 7) * 84 + (k >> 3)) * 1024 + (e & 127) * 8 + (k & 7);
        W2[dst] = __float2bfloat16(v);
    }
    if (idx < 768) biasT[idx] = b0[idx] + b1[idx] + b2[idx];
}

// -------- per-patch: PURE REGISTER, one wave per patch, zero LDS --------
// Fill loops use VERTICAL-FIRST window sums: v_j = okT*u_j + enc_j + okB*d_j,
// then left/right COLUMNS come from neighbor lanes' already-masked v
// (same row => same okT/okB). g16: 10 shfl/iter (was 14); g8/g4: 4 (was 8).
// All shuffles unconditional on the uniform path (R4 EXEC-mask lesson).
__global__ __launch_bounds__(256) void patch_kernel(const float* __restrict__ x,
                                                    const float* __restrict__ dmin,
                                                    __hip_bfloat16* __restrict__ F,
                                                    float* __restrict__ maskout) {
    const int t = threadIdx.x;
    const int w = t >> 6, lane = t & 63;
    const int pid = blockIdx.x * 4 + w;       // wave = patch
    const int b = pid >> 10, n = pid & 1023;
    const int gi = n >> 5, gj = n & 31;
    const int row = lane >> 2, cq = lane & 3, cg = cq * 4;
    const float thr = dmin[b] + 1e-6f;

    const float4 v = *(const float4*)(x + ((size_t)(b * 512 + gi * 16 + row)) * 512 + gj * 16 + cg);
    float enc0, enc1, enc2, enc3;
    ushort4 om;
    {
        const bool v0 = v.x > thr, v1 = v.y > thr, v2 = v.z > thr, v3 = v.w > thr;
        enc0 = v0 ? fmaf(v.x, 0.99999000009999f, 256.0f) : 0.0f;   // 256 + d/1.00001
        enc1 = v1 ? fmaf(v.y, 0.99999000009999f, 256.0f) : 0.0f;
        enc2 = v2 ? fmaf(v.z, 0.99999000009999f, 256.0f) : 0.0f;
        enc3 = v3 ? fmaf(v.w, 0.99999000009999f, 256.0f) : 0.0f;
        om.x = v0 ? 0x3F80 : 0; om.y = v1 ? 0x3F80 : 0;            // bf16(1.0/0.0)
        om.z = v2 ? 0x3F80 : 0; om.w = v3 ? 0x3F80 : 0;
    }

    // ---- pools from initial encoded values (register butterflies) ----
    const float vs0 = enc0 + __shfl(enc0, lane ^ 4);   // vertical row-pair sums
    const float vs1 = enc1 + __shfl(enc1, lane ^ 4);
    const float vs2 = enc2 + __shfl(enc2, lane ^ 4);
    const float vs3 = enc3 + __shfl(enc3, lane ^ 4);
    const float a80 = vs0 + vs1, a81 = vs2 + vs3;      // g8 cells (row>>1,2cq),(row>>1,2cq+1)
    const int r8 = lane >> 3, c8 = lane & 7;
    const int src8 = r8 * 8 + (c8 >> 1);
    const float t80 = __shfl(a80, src8), t81 = __shfl(a81, src8);
    const float sum8 = (c8 & 1) ? t81 : t80;           // encoded 2x2 sum of my g8 cell
    const float N8 = floorf(sum8 * 0.00390625f);
    const float S8 = fmaf(N8, -256.0f, sum8);
    const float mp8 = N8 * 0.25f;
    const float dh8 = (S8 * 0.2500025f) / fmaf(N8, 0.25f, 1e-5f);  // (S/1.00001/4)/(mp8+1e-5)
    float enc8 = (N8 >= 1.0f) ? (256.0f + fmaxf(dh8, 0.0f)) : 0.0f;
    // g4 sums from g8 sums
    const float vp8 = sum8 + __shfl(sum8, lane ^ 8);
    const float sum4w = vp8 + __shfl(vp8, lane ^ 1);   // g4 cell (r8>>1,c8>>1), duplicated
    const int cell4 = lane & 15;
    const int r4 = cell4 >> 2, c4 = cell4 & 3;
    const float s4 = __shfl(sum4w, r4 * 16 + c4 * 2);
    const float N4 = floorf(s4 * 0.00390625f);
    const float S4 = fmaf(N4, -256.0f, s4);
    const float mp4 = N4 * 0.0625f;
    const float dh4 = (S4 * 0.062500625f) / fmaf(N4, 0.0625f, 1e-5f);
    float enc4 = (N4 >= 1.0f) ? (256.0f + fmaxf(dh4, 0.0f)) : 0.0f;

    // ---- g16 fill: vertical-first, 10 shfl/iter ----
    {
        const float okT = (row > 0) ? 1.f : 0.f, okB = (row < 15) ? 1.f : 0.f;
        const float okL = (cq > 0) ? 1.f : 0.f, okR = (cq < 3) ? 1.f : 0.f;
        const int liU = (lane - 4) & 63, liD = (lane + 4) & 63;
        const int liL = (lane - 1) & 63, liR = (lane + 1) & 63;
        for (;;) {
            const float u0 = __shfl(enc0, liU), u1 = __shfl(enc1, liU);
            const float u2 = __shfl(enc2, liU), u3 = __shfl(enc3, liU);
            const float d0 = __shfl(enc0, liD), d1 = __shfl(enc1, liD);
            const float d2 = __shfl(enc2, liD), d3 = __shfl(enc3, liD);
            const float v0 = fmaf(okB, d0, fmaf(okT, u0, enc0));   // column vertical triples
            const float v1 = fmaf(okB, d1, fmaf(okT, u1, enc1));
            const float v2 = fmaf(okB, d2, fmaf(okT, u2, enc2));
            const float v3 = fmaf(okB, d3, fmaf(okT, u3, enc3));
            const float vL = __shfl(v3, liL);      // left col (lane-1 same row: same okT/okB)
            const float vR = __shfl(v0, liR);
            float w0s = fmaf(okL, vL, v0 + v1);
            float w1s = v0 + v1 + v2;
            float w2s = v1 + v2 + v3;
            float w3s = fmaf(okR, vR, v2 + v3);
            asm volatile("" :: "v"(w0s), "v"(w1s), "v"(w2s), "v"(w3s));  // pin (uniform path)
            int fill = 0;
            if (enc0 < 256.f) {
                const float Nf = floorf(w0s * 0.00390625f);
                if (Nf >= 1.f) { enc0 = 256.f + fmaxf(fmaf(Nf, -256.f, w0s), 0.f) * __builtin_amdgcn_rcpf(Nf); fill = 1; }
            }
            if (enc1 < 256.f) {
                const float Nf = floorf(w1s * 0.00390625f);
                if (Nf >= 1.f) { enc1 = 256.f + fmaxf(fmaf(Nf, -256.f, w1s), 0.f) * __builtin_amdgcn_rcpf(Nf); fill = 1; }
            }
            if (enc2 < 256.f) {
                const float Nf = floorf(w2s * 0.00390625f);
                if (Nf >= 1.f) { enc2 = 256.f + fmaxf(fmaf(Nf, -256.f, w2s), 0.f) * __builtin_amdgcn_rcpf(Nf); fill = 1; }
            }
            if (enc3 < 256.f) {
                const float Nf = floorf(w3s * 0.00390625f);
                if (Nf >= 1.f) { enc3 = 256.f + fmaxf(fmaf(Nf, -256.f, w3s), 0.f) * __builtin_amdgcn_rcpf(Nf); fill = 1; }
            }
            if (!__any(fill)) break;
        }
    }
    // ---- emit into blocked layout: base = (mtile*84)*1024 + prow*8 ----
    unsigned short* Fb = (unsigned short*)F + ((size_t)(pid >> 7) * 84) * 1024 + (pid & 127) * 8;
    {
        ushort4 o;
        o.x = f2bf(fmaxf(enc0 - 256.f, 0.f)); o.y = f2bf(fmaxf(enc1 - 256.f, 0.f));
        o.z = f2bf(fmaxf(enc2 - 256.f, 0.f)); o.w = f2bf(fmaxf(enc3 - 256.f, 0.f));
        const int co = row * 16 + cg;
        *(ushort4*)(Fb + (co >> 3) * 1024 + (co & 7)) = o;                 // k = co
        *(ushort4*)(Fb + (32 + (co >> 3)) * 1024 + (co & 7)) = om;         // k = 256+co
    }

    // ---- g8 fill: vertical-first, 4 shfl/iter ----
    {
        const float okU = (r8 > 0) ? 1.f : 0.f;
        const float okD = (r8 < 7) ? 1.f : 0.f;
        const float okL = (c8 > 0) ? 1.f : 0.f;
        const float okR = (c8 < 7) ? 1.f : 0.f;
        const int liU = (lane - 8) & 63, liD = (lane + 8) & 63;
        const int liL = (lane - 1) & 63, liR = (lane + 1) & 63;
        for (int it = 0; it < 8; ++it) {
            const float nU = __shfl(enc8, liU);
            const float nD = __shfl(enc8, liD);
            const float vv = fmaf(okD, nD, fmaf(okU, nU, enc8));   // center==0 when updating
            const float vL = __shfl(vv, liL);
            const float vR = __shfl(vv, liR);
            float s = fmaf(okR, vR, fmaf(okL, vL, vv));
            asm volatile("" :: "v"(s));            // pin to uniform path
            int fill = 0;
            if (enc8 < 256.f) {
                const float Nf = floorf(s * 0.00390625f);
                if (Nf >= 1.f) { enc8 = 256.f + fmaxf(fmaf(Nf, -256.f, s), 0.f) * __builtin_amdgcn_rcpf(Nf); fill = 1; }
            }
            if (!__any(fill)) break;
        }
        Fb[(64 + (lane >> 3)) * 1024 + (lane & 7)] = f2bf(fmaxf(enc8 - 256.f, 0.f));  // k = 512+lane
        Fb[(72 + (lane >> 3)) * 1024 + (lane & 7)] = f2bf(mp8);                        // k = 576+lane
    }

    // ---- g4 fill: vertical-first, 4 shfl/iter (4x4 mirrored across lane groups) ----
    {
        const float okU = (r4 > 0) ? 1.f : 0.f;
        const float okD = (r4 < 3) ? 1.f : 0.f;
        const float okL = (c4 > 0) ? 1.f : 0.f;
        const float okR = (c4 < 3) ? 1.f : 0.f;
        const int liU = (cell4 - 4) & 63, liD = (cell4 + 4) & 63;
        const int liL = (cell4 - 1) & 63, liR = (cell4 + 1) & 63;
        for (int it = 0; it < 4; ++it) {
            const float nU = __shfl(enc4, liU);
            const float nD = __shfl(enc4, liD);
            const float vv = fmaf(okD, nD, fmaf(okU, nU, enc4));
            const float vL = __shfl(vv, liL);
            const float vR = __shfl(vv, liR);
            float s = fmaf(okR, vR, fmaf(okL, vL, vv));
            asm volatile("" :: "v"(s));            // pin to uniform path
            int fill = 0;
            if (enc4 < 256.f) {
                const float Nf = floorf(s * 0.00390625f);
                if (Nf >= 1.f) { enc4 = 256.f + fmaxf(fmaf(Nf, -256.f, s), 0.f) * __builtin_amdgcn_rcpf(Nf); fill = 1; }
            }
            if (!__any(fill)) break;
        }
        if (lane < 16) {
            Fb[(80 + (lane >> 3)) * 1024 + (lane & 7)] = f2bf(fmaxf(enc4 - 256.f, 0.f));      // k = 640+lane
            Fb[(82 + (lane >> 3)) * 1024 + (lane & 7)] = f2bf(mp4);                            // k = 656+lane
        }
        const unsigned long long bal = __ballot(lane < 16 && N4 >= 1.0f);
        if (lane == 0) maskout[pid] = bal ? 1.0f : 0.0f;
    }
}

// -------- GEMM: out[32768][768] = F @ W2^T + biasT, blocked K-major inputs --------
// R12-proven: 128x128, BK=32, 4 waves, 16 KB LDS, XCD swizzle, explicit vmcnt
// drain, contiguous 1-KB staging reads (8 cache lines per global_load_lds).
__global__ __launch_bounds__(256) void gemm_kernel(const short* __restrict__ F,
                                                   const short* __restrict__ W2,
                                                   const float* __restrict__ biasT,
                                                   float* __restrict__ out) {
    constexpr int N = 768;
    const int bid = blockIdx.x;                    // 1536 = 256 m-tiles x 6 n-tiles
    const int swz = (bid & 7) * 192 + (bid >> 3);  // bijective (1536 % 8 == 0)
    const int tm = swz / 6, tn = swz % 6;
    const int m0 = tm * 128, e0 = tn * 128;
    const int t = threadIdx.x;
    const int wave = t >> 6, lane = t & 63;
    const int wm = wave >> 1, wn = wave & 1;
    const int lg = lane & 15, kc = lane >> 4;

    __shared__ short lds_a[4096];   // [4][128][8]
    __shared__ short lds_b[4096];

    const size_t abase = (size_t)tm * 84 * 1024;   // F' m-tile base (elements)
    const size_t bbase = (size_t)tn * 84 * 1024;   // W2' e-tile base

    f32x4 acc[4][4];
    const f32x4 zero = {0.f, 0.f, 0.f, 0.f};
    #pragma unroll
    for (int i = 0; i < 4; ++i)
        #pragma unroll
        for (int j = 0; j < 4; ++j) acc[i][j] = zero;

    for (int kb = 0; kb < 672; kb += 32) {
        const int kbc = kb >> 3;                   // global k-chunk of this K-step
        __syncthreads();   // all waves' LDS reads of prev tile complete
        #pragma unroll
        for (int si = 0; si < 2; ++si) {
            const int s = wave * 2 + si;           // 8 slots of 1 KB each
            const int kccl = s >> 1, half = s & 1;
            const int row = half * 64 + lane;      // per-lane: contiguous 16B each
            async_copy16(F  + abase + (size_t)(kbc + kccl) * 1024 + row * 8, &lds_a[s * 512]);
            async_copy16(W2 + bbase + (size_t)(kbc + kccl) * 1024 + row * 8, &lds_b[s * 512]);
        }
        asm volatile("s_waitcnt vmcnt(0) lgkmcnt(0)" ::: "memory");  // explicit DMA drain
        __syncthreads();   // publish staged tile to all waves

        bf16x8 af[4], bfr[4];
        #pragma unroll
        for (int i = 0; i < 4; ++i) {
            af[i]  = *(const bf16x8*)&lds_a[(kc * 128 + wm * 64 + i * 16 + lg) * 8];
            bfr[i] = *(const bf16x8*)&lds_b[(kc * 128 + wn * 64 + i * 16 + lg) * 8];
        }
        #pragma unroll
        for (int i = 0; i < 4; ++i)
            #pragma unroll
            for (int j = 0; j < 4; ++j)
                acc[i][j] = __builtin_amdgcn_mfma_f32_16x16x32_bf16(af[i], bfr[j], acc[i][j], 0, 0, 0);
    }

    // epilogue: C/D layout col=lane&15, row=(lane>>4)*4+reg (m89-verified)
    const int rbase = (lane >> 4) * 4;
    #pragma unroll
    for (int j = 0; j < 4; ++j) {
        const int e = e0 + wn * 64 + j * 16 + lg;
        const float bs = biasT[e];
        #pragma unroll
        for (int i = 0; i < 4; ++i) {
            const int mr = m0 + wm * 64 + i * 16 + rbase;
            #pragma unroll
            for (int r = 0; r < 4; ++r)
                out[(size_t)(mr + r) * N + e] = acc[i][j][r] + bs;
        }
    }
}

extern "C" void kernel_launch(void* const* d_in, const int* in_sizes, int n_in,
                              void* d_out, int out_size, void* d_ws, size_t ws_size,
                              hipStream_t stream) {
    const float* x  = (const float*)d_in[0];
    const float* w0 = (const float*)d_in[1];
    const float* b0 = (const float*)d_in[2];
    const float* w1 = (const float*)d_in[3];
    const float* b1 = (const float*)d_in[4];
    const float* w2 = (const float*)d_in[5];
    const float* b2 = (const float*)d_in[6];
    float* out = (float*)d_out;

    char* ws = (char*)d_ws;
    __hip_bfloat16* F   = (__hip_bfloat16*)ws;
    __hip_bfloat16* W2  = (__hip_bfloat16*)(ws + 44040192);
    float* biasT        = (float*)(ws + 45072384);
    float* partial      = (float*)(ws + 45075456);
    float* dmin         = (float*)(ws + 45077504);
    float* maskout      = out + 25165824;   // feat is 32*1024*768

    min_partial_kernel<<<512, 256, 0, stream>>>(x, partial);
    min_final_kernel<<<1, 64, 0, stream>>>(partial, dmin);
    prep_kernel<<<2016, 256, 0, stream>>>(w0, b0, w1, b1, w2, b2, W2, biasT);
    patch_kernel<<<8192, 256, 0, stream>>>(x, dmin, F, maskout);
    gemm_kernel<<<1536, 256, 0, stream>>>((const short*)F, (const short*)W2, biasT, out);
}